// Round 7
// baseline (145.733 us; speedup 1.0000x reference)
//
#include <hip/hip_runtime.h>

// Harness promotes float16 tensors to float32: x, scales, out are f32;
// weight_packed is int32, one byte (2 nibbles) per element.
#define M 32
#define N 11008
#define K 4096
#define NGROUPS 32
#define BN 64                // n-rows per block (16 per wave)
#define KSPLIT 16            // k-split across blocks
#define KRANGE (K / KSPLIT)  // 256 k per block, single shot (no k-loop)
#define MN (M * N)

typedef _Float16 half8 __attribute__((ext_vector_type(8))); // 4 VGPRs
typedef _Float16 half4 __attribute__((ext_vector_type(4)));
typedef float floatx4 __attribute__((ext_vector_type(4)));

// LDS rows stored in PAIRS (two 512B rows contiguous = one 1KB gll16 per wave)
// with 16B pad per pair to spread banks across pairs.
#define WPAIR 260 // ints per weight row-pair: 2*128 + 4 pad (1040 B)
#define XPAIR 520 // halves per x row-pair:    2*256 + 8 pad (1040 B)

__device__ inline void gll16(const void* g, void* l) {
    __builtin_amdgcn_global_load_lds(
        (const __attribute__((address_space(1))) unsigned int*)g,
        (__attribute__((address_space(3))) unsigned int*)l, 16, 0, 0);
}

// ---- pre-pass: x f32 -> f16 (512 KB -> 256 KB in d_ws) ----
__global__ __launch_bounds__(512) void xcvt_kernel(
    const float* __restrict__ x, _Float16* __restrict__ xf)
{
    int i = (blockIdx.x * 512 + threadIdx.x) * 4; // M*K = 131072 = 64*512*4
    float4 v = *(const float4*)(x + i);
    half4 h;
    h[0] = (_Float16)v.x; h[1] = (_Float16)v.y;
    h[2] = (_Float16)v.z; h[3] = (_Float16)v.w;
    *(half4*)(xf + i) = h;
}

__global__ __launch_bounds__(256) void int4_gemm_kernel(
    const _Float16* __restrict__ xf,  // [M][K] f16 (pre-converted)
    const int* __restrict__ wp,       // [N][K/2] int32, 2 nibbles each
    const float* __restrict__ scales, // [N][NGROUPS] f32
    float* __restrict__ part)         // [KSPLIT][M][N] f32 partials
{
    __shared__ int wsh[32 * WPAIR];      // 64 w-rows: 33.3 KB
    __shared__ _Float16 xs[16 * XPAIR];  // 32 x-rows: 16.6 KB

    const int t    = threadIdx.x;
    const int lane = t & 63;
    const int w    = t >> 6;        // wave id -> n-subtile [w*16, w*16+16)
    const int n0   = blockIdx.x * BN;
    const int ks   = blockIdx.y;    // k-split index: k in [ks*256, ks*256+256)
    const int row  = lane & 15;
    const int quad = lane >> 4;

    const int nw = n0 + w * 16 + row; // this lane's weight row / output col
    // scales for the two 128-k groups in this block's k-range (L2-resident;
    // VMEM returns are in-order, so these complete before the gll drain)
    const float s0 = scales[nw * NGROUPS + ks * 2];
    const float s1 = scales[nw * NGROUPS + ks * 2 + 1];

    // ---- stage weights: 32 row-pairs x 1KB, 8 gll per wave ----
    #pragma unroll
    for (int i = 0; i < 8; ++i) {
        int p = w * 8 + i;
        int r = 2 * p + (lane >> 5);
        const int* g = wp + (long)(n0 + r) * (K / 2) + ks * (KRANGE / 2) + (lane & 31) * 4;
        gll16(g, &wsh[p * WPAIR]);
    }
    // ---- stage x: 16 row-pairs x 1KB, 4 gll per wave ----
    #pragma unroll
    for (int i = 0; i < 4; ++i) {
        int p = w * 4 + i;
        int m = 2 * p + (lane >> 5);
        const _Float16* g = xf + m * K + ks * KRANGE + (lane & 31) * 8;
        gll16(g, &xs[p * XPAIR]);
    }
    __syncthreads(); // single barrier: drains gll queue once per block

    const half8 c1032 = (half8)(_Float16)1032.0f; // 0x6408, exact
    floatx4 acc0 = {0.f, 0.f, 0.f, 0.f};
    floatx4 acc1 = {0.f, 0.f, 0.f, 0.f};

    const int wr    = w * 16 + row;                              // local w-row
    const int wbase = (wr >> 1) * WPAIR + (wr & 1) * 128 + quad * 4;
    const int xbase = (row >> 1) * XPAIR + (row & 1) * 256 + quad * 8;

    #pragma unroll
    for (int g = 0; g < 2; ++g) {        // two 128-k scale groups
        floatx4 t0 = {0.f, 0.f, 0.f, 0.f};
        floatx4 t1 = {0.f, 0.f, 0.f, 0.f};
        #pragma unroll
        for (int kk = 0; kk < 4; ++kk) { // 4 MFMA k-steps of 32
            const int kq = g * 4 + kk;
            int4 wv = *(const int4*)&wsh[wbase + kq * 16];
            uint4 uw;
            {
                unsigned int b;
                b = (unsigned int)wv.x; uw.x = ((b | (b << 12)) & 0x000F000Fu) | 0x64006400u;
                b = (unsigned int)wv.y; uw.y = ((b | (b << 12)) & 0x000F000Fu) | 0x64006400u;
                b = (unsigned int)wv.z; uw.z = ((b | (b << 12)) & 0x000F000Fu) | 0x64006400u;
                b = (unsigned int)wv.w; uw.w = ((b | (b << 12)) & 0x000F000Fu) | 0x64006400u;
            }
            half8 bfrag = __builtin_bit_cast(half8, uw) - c1032; // exact (nib-8)
            half8 a0 = *(const half8*)&xs[xbase + kq * 32];
            half8 a1 = *(const half8*)&xs[xbase + 8 * XPAIR + kq * 32]; // m+16
            t0 = __builtin_amdgcn_mfma_f32_16x16x32_f16(a0, bfrag, t0, 0, 0, 0);
            t1 = __builtin_amdgcn_mfma_f32_16x16x32_f16(a1, bfrag, t1, 0, 0, 0);
        }
        const float s = g ? s1 : s0;
        #pragma unroll
        for (int r = 0; r < 4; ++r) {
            acc0[r] += s * t0[r]; // fp32 scale application, matches reference
            acc1[r] += s * t1[r];
        }
    }

    // ---- epilogue: coalesced partial stores (full 64B lines, no atomics) ----
    // C/D layout: col(n) = lane&15, row(m) = quad*4 + r
    float* po = part + (long)ks * MN;
    #pragma unroll
    for (int r = 0; r < 4; ++r) {
        int mr = quad * 4 + r;
        po[mr * N + nw]        = acc0[r];
        po[(mr + 16) * N + nw] = acc1[r];
    }
}

// ---- reduce the 16 k-split partials -> out ----
__global__ __launch_bounds__(256) void reduce_kernel(
    const float* __restrict__ part, float* __restrict__ out)
{
    int o = blockIdx.x * 256 + threadIdx.x; // MN = 352256 = 1376*256
    float s = 0.f;
    #pragma unroll
    for (int j = 0; j < KSPLIT; ++j) s += part[(long)j * MN + o];
    out[o] = s;
}

extern "C" void kernel_launch(void* const* d_in, const int* in_sizes, int n_in,
                              void* d_out, int out_size, void* d_ws, size_t ws_size,
                              hipStream_t stream) {
    const float* x      = (const float*)d_in[0];
    const int* wp       = (const int*)d_in[1];
    const float* scales = (const float*)d_in[2];
    float* out          = (float*)d_out;

    _Float16* xf16 = (_Float16*)d_ws;                       // 256 KB
    float* part    = (float*)((char*)d_ws + (size_t)M * K * 2); // 22.5 MB

    xcvt_kernel<<<dim3((M * K) / (512 * 4)), 512, 0, stream>>>(x, xf16);
    int4_gemm_kernel<<<dim3(N / BN, KSPLIT), 256, 0, stream>>>(xf16, wp, scales, part);
    reduce_kernel<<<dim3(MN / 256), 256, 0, stream>>>(part, out);
}